// Round 9
// baseline (151.855 us; speedup 1.0000x reference)
//
#include <hip/hip_runtime.h>

// Per-sample depthwise 7x7 cross-correlation, NHWC, SAME padding.
// inputs:  [B,H,W,C] fp32, kernels: [B,7,7,C] fp32, out: [B,H,W,C] fp32.
// out[b,y,x,c] = sum_{i,j} in[b, y+i-3, x+j-3, c] * ker[b,i,j,c]  (zero pad)
//
// R9 = R8 (fp16 dot2, fp32 accum, weights packed in LDS) +
//  - pass loop unrolled x7 with STATIC accumulator-ring rotation
//    (slot = (r+6-i) mod 7 folds at compile time -> no 28-mov shift per pass)
//  - 512-thread blocks, YSPLIT=2 (NPASS=70=7x10), 4 blocks/CU.
// Register budget stays in the 64-VGPR tier by construction; no occupancy
// attributes (they made the allocator spill in R2/R6).

#define BB 32
#define HH 128
#define WW 128
#define CC 128
#define KH 7
#define KW 7

#define XPT 4                        // x outputs per thread
#define NTAP (XPT + KW - 1)          // 10 input columns per row per thread
#define XG 4                         // x-groups per block (512 threads / 128 c)
#define SLABW (XG * XPT)             // 16 output columns per block
#define NXS (WW / SLABW)             // 8 x-slabs
#define YSPLIT 2
#define YROWS (HH / YSPLIT)          // 64 output rows per block
#define GRID (BB * NXS * YSPLIT)     // 512 blocks = 4 per CU (8 waves each)
#define WSLOTS 28                    // per-c packed-weight uints (7 rows x 4 pairs)
#define NPASS (YROWS + KH - 1)       // 70 = 7 x 10 single-row passes

typedef _Float16 half2_t __attribute__((ext_vector_type(2)));

static __device__ __forceinline__ half2_t pk(float a, float b) {
#if __has_builtin(__builtin_amdgcn_cvt_pkrtz)
    return __builtin_bit_cast(half2_t, __builtin_amdgcn_cvt_pkrtz(a, b));
#else
    half2_t r; r.x = (_Float16)a; r.y = (_Float16)b; return r;
#endif
}

static __device__ __forceinline__ float dot2f(unsigned w, half2_t t, float c) {
#if __has_builtin(__builtin_amdgcn_fdot2)
    return __builtin_amdgcn_fdot2(__builtin_bit_cast(half2_t, w), t, c, false);
#else
    half2_t wv = __builtin_bit_cast(half2_t, w);
    return fmaf((float)wv.x, (float)t.x, fmaf((float)wv.y, (float)t.y, c));
#endif
}

__global__ __launch_bounds__(512) void crossconv_kernel(
    const float* __restrict__ in,
    const float* __restrict__ ker,
    float* __restrict__ out)
{
    __shared__ unsigned lds_w[CC * WSLOTS];   // 14336 B

    const int tid = threadIdx.x;
    const int c  = tid & (CC - 1);   // lanes contiguous in c -> coalesced
    const int xg = __builtin_amdgcn_readfirstlane(tid >> 7);   // 0..3, wave-uniform

    // Bijective XCD swizzle (GRID=512, 64 blocks/XCD = 4 whole samples).
    const int bid = blockIdx.x;
    const int swz = (bid & 7) * (GRID / 8) + (bid >> 3);
    const int b  = swz >> 4;         // 16 blocks per sample
    const int xs = (swz >> 1) & 7;
    const int yh = swz & 1;
    const int x0 = xs * SLABW + xg * XPT;  // wave-uniform (scalar)
    const int y0 = yh * YROWS;

    // Stage packed weights into LDS: slot s (0..27) -> row i=s>>2, pair q=s&3.
    // q<3: (w[i][2q], w[i][2q+1]); q==3: (w[i][6], 0).
    {
        const float* kb = ker + ((size_t)b * KH * KW) * CC + c;
        for (int s = xg; s < WSLOTS; s += XG) {
            const int i = s >> 2, q = s & 3;
            half2_t pr;
            if (q < 3) {
                const int f0 = i * KW + 2 * q;
                pr = pk(kb[f0 * CC], kb[(f0 + 1) * CC]);
            } else {
                pr = pk(kb[(i * KW + 6) * CC], 0.0f);
            }
            lds_w[c * WSLOTS + s] = __builtin_bit_cast(unsigned, pr);
        }
    }
    __syncthreads();

    const float* ib = in  + ((size_t)b * HH * WW) * CC;
    float*       ob = out + ((size_t)b * HH * WW) * CC;
    const unsigned* wlds = &lds_w[c * WSLOTS];

    const bool interior = (x0 >= 3) && (x0 + XPT + 2 < WW);

    auto load_taps = [&](float* t, int yi) {
        if (yi < 0 || yi >= HH) {
            #pragma unroll
            for (int j = 0; j < NTAP; ++j) t[j] = 0.0f;
            return;
        }
        const float* row = ib + (size_t)yi * WW * CC + c;  // per-lane part: c only
        if (interior) {
            #pragma unroll
            for (int j = 0; j < NTAP; ++j)
                t[j] = row[(x0 - 3 + j) * CC];             // scalar offsets
        } else {
            #pragma unroll
            for (int j = 0; j < NTAP; ++j) {
                const int xx = x0 - 3 + j;
                t[j] = (xx >= 0 && xx < WW) ? row[xx * CC] : 0.0f;
            }
        }
    };

    // Fixed-storage accumulator ring. At global pass p, kernel row i feeds
    // PHYSICAL slot (p + 6 - i) mod 7; slot (p mod 7) completes and is
    // re-zeroed for reuse. With the inner loop unrolled, p mod 7 == r is a
    // compile-time constant -> no data movement.
    float acc[KH][XPT];
    #pragma unroll
    for (int s = 0; s < KH; ++s)
        #pragma unroll
        for (int xo = 0; xo < XPT; ++xo) acc[s][xo] = 0.0f;

    const int yi0 = y0 - 3;

    // Packed taps for the CURRENT pass row:
    // e[k] = (t[2k], t[2k+1]) k=0..4 ; o[k] = (t[2k+1], t[2k+2]) k=0..3,
    // o[4] = (t[9], 0).  Even xo: e[xo/2 + q]; odd xo: o[(xo-1)/2 + q].
    float t[NTAP];
    half2_t e[5], o[5];
    load_taps(t, yi0);
    #pragma unroll
    for (int k = 0; k < 5; ++k) e[k] = pk(t[2 * k], t[2 * k + 1]);
    #pragma unroll
    for (int k = 0; k < 4; ++k) o[k] = pk(t[2 * k + 1], t[2 * k + 2]);
    o[4] = pk(t[9], 0.0f);

    #pragma unroll 1
    for (int pp = 0; pp < NPASS / 7; ++pp) {
        #pragma unroll
        for (int r = 0; r < 7; ++r) {
            const int p  = pp * 7 + r;
            const int yi = yi0 + p;

            // Issue next row's tap loads; dot pass hides the latency.
            // (Past the final pass, request row HH -> zero-fill path.)
            load_taps(t, (p + 1 < NPASS) ? (yi + 1) : HH);

            // Keep per-pass LDS weight reads in the loop (hoisting 28 pairs
            // would blow the 64-VGPR tier and spill).
            asm volatile("" ::: "memory");

            #pragma unroll
            for (int i = 0; i < KH; ++i) {
                const uint4 wq = *(const uint4*)(wlds + i * 4);  // kernel row i
                const int s = (r + 6 - i) % 7;                   // compile-time
                #pragma unroll
                for (int xo = 0; xo < XPT; ++xo) {
                    float a = acc[s][xo];
                    if ((xo & 1) == 0) {
                        const int k0 = xo >> 1;
                        a = dot2f(wq.x, e[k0],     a);
                        a = dot2f(wq.y, e[k0 + 1], a);
                        a = dot2f(wq.z, e[k0 + 2], a);
                        a = dot2f(wq.w, e[k0 + 3], a);
                    } else {
                        const int k0 = (xo - 1) >> 1;
                        a = dot2f(wq.x, o[k0],     a);
                        a = dot2f(wq.y, o[k0 + 1], a);
                        a = dot2f(wq.z, o[k0 + 2], a);
                        a = dot2f(wq.w, o[k0 + 3], a);
                    }
                    acc[s][xo] = a;
                }
            }

            // Slot r completes as output row y = yi - 3 (wave-uniform guard).
            const int y = yi - 3;
            if (y >= y0) {
                float* orow = ob + ((size_t)y * WW + x0) * CC + c;
                #pragma unroll
                for (int xo = 0; xo < XPT; ++xo)
                    orow[xo * CC] = acc[r][xo];
            }
            #pragma unroll
            for (int xo = 0; xo < XPT; ++xo) acc[r][xo] = 0.0f;

            // Pack the prefetched row for the next pass.
            #pragma unroll
            for (int k = 0; k < 5; ++k) e[k] = pk(t[2 * k], t[2 * k + 1]);
            #pragma unroll
            for (int k = 0; k < 4; ++k) o[k] = pk(t[2 * k + 1], t[2 * k + 2]);
            o[4] = pk(t[9], 0.0f);
        }
    }
}

extern "C" void kernel_launch(void* const* d_in, const int* in_sizes, int n_in,
                              void* d_out, int out_size, void* d_ws, size_t ws_size,
                              hipStream_t stream) {
    const float* in  = (const float*)d_in[0];
    const float* ker = (const float*)d_in[1];
    float*       out = (float*)d_out;

    crossconv_kernel<<<GRID, 512, 0, stream>>>(in, ker, out);
}

// Round 10
// 142.930 us; speedup vs baseline: 1.0624x; 1.0624x over previous
//
#include <hip/hip_runtime.h>

// Per-sample depthwise 7x7 cross-correlation, NHWC, SAME padding.
// inputs:  [B,H,W,C] fp32, kernels: [B,7,7,C] fp32, out: [B,H,W,C] fp32.
// out[b,y,x,c] = sum_{i,j} in[b, y+i-3, x+j-3, c] * ker[b,i,j,c]  (zero pad)
//
// R10 = R8's fp16-dot2 path + TWO input rows per weight pass (8-slot ring):
// each ds_read_b128 weight quad feeds 8 dot2 (4 xo x 2 rows) -> LDS traffic
// halved, ring-shift movs halved per output row. No prefetch staging across
// passes (TLP from 32 waves/CU hides load latency); both rows' 20 loads are
// issued back-to-back so packing row A overlaps row B's inflight loads.
// Register demand ~58-62: inside the 64-VGPR tier by construction. NO
// occupancy attributes (they forced spills in R2/R6) and NO multi-pass
// unrolling (R9: x7 unroll -> 108 VGPRs).

#define BB 32
#define HH 128
#define WW 128
#define CC 128
#define KH 7
#define KW 7

#define XPT 4                        // x outputs per thread
#define NTAP (XPT + KW - 1)          // 10 input columns per row per thread
#define XG 8                         // x-groups per block (1024 threads / 128 c)
#define SLABW (XG * XPT)             // 32 output columns per block
#define NXS (WW / SLABW)             // 4 x-slabs
#define YSPLIT 4
#define YROWS (HH / YSPLIT)          // 32 output rows per block
#define GRID (BB * NXS * YSPLIT)     // 512 blocks = 2 per CU
#define WSLOTS 28                    // per-c packed-weight uints (7 rows x 4 pairs)
#define NPASS ((YROWS + KH - 1) / 2) // 19 double-row passes (38 input rows)

typedef _Float16 half2_t __attribute__((ext_vector_type(2)));

static __device__ __forceinline__ half2_t pk(float a, float b) {
#if __has_builtin(__builtin_amdgcn_cvt_pkrtz)
    return __builtin_bit_cast(half2_t, __builtin_amdgcn_cvt_pkrtz(a, b));
#else
    half2_t r; r.x = (_Float16)a; r.y = (_Float16)b; return r;
#endif
}

static __device__ __forceinline__ float dot2f(unsigned w, half2_t t, float c) {
#if __has_builtin(__builtin_amdgcn_fdot2)
    return __builtin_amdgcn_fdot2(__builtin_bit_cast(half2_t, w), t, c, false);
#else
    half2_t wv = __builtin_bit_cast(half2_t, w);
    return fmaf((float)wv.x, (float)t.x, fmaf((float)wv.y, (float)t.y, c));
#endif
}

__global__ __launch_bounds__(1024) void crossconv_kernel(
    const float* __restrict__ in,
    const float* __restrict__ ker,
    float* __restrict__ out)
{
    __shared__ unsigned lds_w[CC * WSLOTS];   // 14336 B

    const int tid = threadIdx.x;
    const int c  = tid & (CC - 1);   // lanes contiguous in c -> coalesced
    const int xg = __builtin_amdgcn_readfirstlane(tid >> 7);   // 0..7, wave-uniform

    // Bijective XCD swizzle (GRID=512, 64 blocks/XCD = 4 whole samples).
    const int bid = blockIdx.x;
    const int swz = (bid & 7) * (GRID / 8) + (bid >> 3);
    const int b  = swz >> 4;         // 16 blocks per sample
    const int xs = (swz >> 2) & 3;
    const int yh = swz & 3;
    const int x0 = xs * SLABW + xg * XPT;  // wave-uniform (scalar)
    const int y0 = yh * YROWS;

    // Stage packed weights into LDS: slot s (0..27) -> row i=s>>2, pair q=s&3.
    // q<3: (w[i][2q], w[i][2q+1]); q==3: (w[i][6], 0).
    {
        const float* kb = ker + ((size_t)b * KH * KW) * CC + c;
        for (int s = xg; s < WSLOTS; s += XG) {
            const int i = s >> 2, q = s & 3;
            half2_t pr;
            if (q < 3) {
                const int f0 = i * KW + 2 * q;
                pr = pk(kb[f0 * CC], kb[(f0 + 1) * CC]);
            } else {
                pr = pk(kb[(i * KW + 6) * CC], 0.0f);
            }
            lds_w[c * WSLOTS + s] = __builtin_bit_cast(unsigned, pr);
        }
    }
    __syncthreads();

    const float* ib = in  + ((size_t)b * HH * WW) * CC;
    float*       ob = out + ((size_t)b * HH * WW) * CC;
    const unsigned* wlds = &lds_w[c * WSLOTS];

    const bool interior = (x0 >= 3) && (x0 + XPT + 2 < WW);

    auto load_taps = [&](float* t, int yi) {
        if (yi < 0 || yi >= HH) {
            #pragma unroll
            for (int j = 0; j < NTAP; ++j) t[j] = 0.0f;
            return;
        }
        const float* row = ib + (size_t)yi * WW * CC + c;  // per-lane part: c only
        if (interior) {
            #pragma unroll
            for (int j = 0; j < NTAP; ++j)
                t[j] = row[(x0 - 3 + j) * CC];             // scalar offsets
        } else {
            #pragma unroll
            for (int j = 0; j < NTAP; ++j) {
                const int xx = x0 - 3 + j;
                t[j] = (xx >= 0 && xx < WW) ? row[xx * CC] : 0.0f;
            }
        }
    };

    // 8-slot sliding ring: before a pass on rows (yi, yi+1), acc[s] holds the
    // partial for output row y = yi-3+s, s=0..7.
    float acc[KH + 1][XPT];
    #pragma unroll
    for (int s = 0; s < KH + 1; ++s)
        #pragma unroll
        for (int xo = 0; xo < XPT; ++xo) acc[s][xo] = 0.0f;

    const int yi0 = y0 - 3;

    #pragma unroll 1
    for (int p = 0; p < NPASS; ++p) {
        const int yi = yi0 + 2 * p;

        // Issue both rows' loads back-to-back; counted vmcnt lets row-A
        // packing start while row-B loads are still in flight.
        float ta[NTAP], tb[NTAP];
        load_taps(ta, yi);
        load_taps(tb, yi + 1);

        // Pack row A: eA[k]=(t[2k],t[2k+1]), oA[k]=(t[2k+1],t[2k+2]), o[4]=(t9,0).
        half2_t eA[5], oA[5], eB[5], oB[5];
        #pragma unroll
        for (int k = 0; k < 5; ++k) eA[k] = pk(ta[2 * k], ta[2 * k + 1]);
        #pragma unroll
        for (int k = 0; k < 4; ++k) oA[k] = pk(ta[2 * k + 1], ta[2 * k + 2]);
        oA[4] = pk(ta[9], 0.0f);
        #pragma unroll
        for (int k = 0; k < 5; ++k) eB[k] = pk(tb[2 * k], tb[2 * k + 1]);
        #pragma unroll
        for (int k = 0; k < 4; ++k) oB[k] = pk(tb[2 * k + 1], tb[2 * k + 2]);
        oB[4] = pk(tb[9], 0.0f);

        // Keep per-pass LDS weight reads in the loop (hoisting 28 pairs would
        // blow the 64-VGPR tier and spill).
        asm volatile("" ::: "memory");

        // Row yi feeds slot 6-i with kernel row i; row yi+1 feeds slot 7-i.
        #pragma unroll
        for (int i = 0; i < KH; ++i) {
            const uint4 wq = *(const uint4*)(wlds + i * 4);   // kernel row i
            #pragma unroll
            for (int xo = 0; xo < XPT; ++xo) {
                float a = acc[6 - i][xo];
                float a2 = acc[7 - i][xo];
                if ((xo & 1) == 0) {
                    const int k0 = xo >> 1;
                    a  = dot2f(wq.x, eA[k0],     a);
                    a  = dot2f(wq.y, eA[k0 + 1], a);
                    a  = dot2f(wq.z, eA[k0 + 2], a);
                    a  = dot2f(wq.w, eA[k0 + 3], a);
                    a2 = dot2f(wq.x, eB[k0],     a2);
                    a2 = dot2f(wq.y, eB[k0 + 1], a2);
                    a2 = dot2f(wq.z, eB[k0 + 2], a2);
                    a2 = dot2f(wq.w, eB[k0 + 3], a2);
                } else {
                    const int k0 = (xo - 1) >> 1;
                    a  = dot2f(wq.x, oA[k0],     a);
                    a  = dot2f(wq.y, oA[k0 + 1], a);
                    a  = dot2f(wq.z, oA[k0 + 2], a);
                    a  = dot2f(wq.w, oA[k0 + 3], a);
                    a2 = dot2f(wq.x, oB[k0],     a2);
                    a2 = dot2f(wq.y, oB[k0 + 1], a2);
                    a2 = dot2f(wq.z, oB[k0 + 2], a2);
                    a2 = dot2f(wq.w, oB[k0 + 3], a2);
                }
                acc[6 - i][xo] = a;
                acc[7 - i][xo] = a2;
            }
        }

        // Outputs y = yi-3 (slot 0) and y = yi-2 (slot 1) are complete.
        {
            const int y = yi - 3;
            if (y >= y0) {
                float* orow = ob + ((size_t)y * WW + x0) * CC + c;
                #pragma unroll
                for (int xo = 0; xo < XPT; ++xo)
                    orow[xo * CC] = acc[0][xo];
            }
            if (y + 1 >= y0) {   // upper bound guaranteed by loop end
                float* orow = ob + ((size_t)(y + 1) * WW + x0) * CC + c;
                #pragma unroll
                for (int xo = 0; xo < XPT; ++xo)
                    orow[xo * CC] = acc[1][xo];
            }
        }

        // Shift ring by 2, open two fresh slots.
        #pragma unroll
        for (int s = 0; s < KH - 1; ++s)
            #pragma unroll
            for (int xo = 0; xo < XPT; ++xo) acc[s][xo] = acc[s + 2][xo];
        #pragma unroll
        for (int xo = 0; xo < XPT; ++xo) {
            acc[KH - 1][xo] = 0.0f;
            acc[KH][xo]     = 0.0f;
        }
    }
}

extern "C" void kernel_launch(void* const* d_in, const int* in_sizes, int n_in,
                              void* d_out, int out_size, void* d_ws, size_t ws_size,
                              hipStream_t stream) {
    const float* in  = (const float*)d_in[0];
    const float* ker = (const float*)d_in[1];
    float*       out = (float*)d_out;

    crossconv_kernel<<<GRID, 1024, 0, stream>>>(in, ker, out);
}